// Round 13
// baseline (136.911 us; speedup 1.0000x reference)
//
#include <hip/hip_runtime.h>
#include <hip/hip_bf16.h>
#include <math.h>

static constexpr int T_TOK = 16384;   // 4*4096 tokens
static constexpr int E     = 256;     // experts
static constexpr int H     = 2048;    // hidden dim

typedef __attribute__((ext_vector_type(8))) _Float16       f16x8;
typedef __attribute__((ext_vector_type(8))) unsigned short u16x8;
typedef __attribute__((ext_vector_type(4))) float          f32x4;

// 2-way f16 split of a PRE-SCALED value: xs == h + m + eps, |eps| <~ 2^-22|xs|.
__device__ __forceinline__ void split2(float xs, unsigned short& h,
                                       unsigned short& m) {
    _Float16 hh = (_Float16)xs;        // RN f32->f16
    float fh = (float)hh;
    float r  = xs - fh;                // exact in f32
    _Float16 mm = (_Float16)r;         // RN
    h = *(unsigned short*)&hh; m = *(unsigned short*)&mm;
}

// async 16B global -> LDS (dest = wave-uniform base + lane*16)
__device__ __forceinline__ void gload_lds16(const unsigned short* g,
                                            unsigned short* l) {
    __builtin_amdgcn_global_load_lds(
        (const __attribute__((address_space(1))) unsigned int*)g,
        (__attribute__((address_space(3))) unsigned int*)l, 16, 0, 0);
}

// ---------------------------------------------------------------------------
// Kernel 0: split W*256 [256][2048] fp32 into two f16 planes (same layout).
// ---------------------------------------------------------------------------
__global__ __launch_bounds__(256) void prep_w(const float* __restrict__ W,
                                              unsigned short* __restrict__ Wh,
                                              unsigned short* __restrict__ Wm) {
    const int i = (blockIdx.x * 256 + threadIdx.x) * 4;
    float4 x = *(const float4*)(W + i);
    unsigned short h[4], m[4];
    split2(x.x * 256.f, h[0], m[0]);
    split2(x.y * 256.f, h[1], m[1]);
    split2(x.z * 256.f, h[2], m[2]);
    split2(x.w * 256.f, h[3], m[3]);
#pragma unroll
    for (int q = 0; q < 4; ++q) { Wh[i+q] = h[q]; Wm[i+q] = m[q]; }
}

// ---------------------------------------------------------------------------
// Kernel 1: partial logits via f16x2 MFMA, THREE passes (hh,hm,mh — the mm
// term is ~2e-8 on unit logits, an order below the existing 2^-22 budget).
// Block = 128 tokens x 128 experts, 256 threads (4 waves, 2Mx2N), wave tile
// 64x64 = 4x4 frags of mfma_f32_16x16x32_f16. BK=64 (NK=8 at nsplit=4).
// Single-buffered 64 KB LDS; per step:
//   [MFMA on tile kt] barrier-A -> issue B(kt+1) gloads -> A_STAGE(kt+1)
//   (consumes X regs loaded LAST step; X HBM latency hidden under the 96
//   MFMAs) -> issue X(kt+2) into the freed regs -> s_waitcnt vmcnt(8)
//   (retires exactly the 8 B gloads; X stays in flight across the barrier)
//   lgkmcnt(0) -> s_barrier.
// vmcnt FIFO audit (steady state): at barrier-A outstanding=[X(kt+1)x8];
// +B(kt+1)x8 -> [Xx8,Bx8]; A_STAGE waits X (oldest 8) -> [Bx8]; +X(kt+2)x8
// -> [Bx8,Xx8]; vmcnt(8) retires the 8 oldest = all B. Tail (kt+2==NK):
// no X issued -> vmcnt(0).
// ---------------------------------------------------------------------------
__global__ __launch_bounds__(256) void gemm_logits(
        const float* __restrict__ X,
        const unsigned short* __restrict__ Wh,
        const unsigned short* __restrict__ Wm,
        float* __restrict__ Cp, int klen) {
    __shared__ __align__(16) unsigned short As[2][8][128][8];   // 32 KB
    __shared__ __align__(16) unsigned short Bs[2][8][128][8];   // 32 KB

    const int tid  = threadIdx.x;
    const int lane = tid & 63;
    const int wid  = tid >> 6;            // 0..3
    const int wm   = wid >> 1, wn = wid & 1;   // 2M x 2N
    const int kz   = blockIdx.z;
    const int kbase = kz * klen;
    const int TB   = blockIdx.y * 128;
    const int eb   = blockIdx.x * 128;

    // A staging: thread owns row=tid>>1, k-half=(tid&1)*32 of the BK=64 tile
    const int srow = tid >> 1;
    const int kc0  = (tid & 1) * 4;       // first of four 8-k chunks
    const float* Xp = X + (size_t)(TB + srow) * H + kbase + (tid & 1) * 32;

    // B staging: 4 x 16B gloads per plane; linear slot s = tid + 256q
    //   -> (kc = (tid>>7) + 2q, row = tid&127)
    const int brow = tid & 127;
    const int bkc  = tid >> 7;            // 0..1
    const unsigned short* WB0 = Wh + (size_t)(eb + brow) * H + kbase + bkc * 8;
    const unsigned short* WB1 = Wm + (size_t)(eb + brow) * H + kbase + bkc * 8;

    const int frow = lane & 15;
    const int fkc  = lane >> 4;           // k-chunk 0..3 within a 32-k half

    f32x4 acc[4][4];
#pragma unroll
    for (int i = 0; i < 4; ++i)
#pragma unroll
        for (int j = 0; j < 4; ++j) acc[i][j] = (f32x4){0.f, 0.f, 0.f, 0.f};

    const int NK = klen / 64;             // nsplit 4/2/1 -> 8/16/32

    // ---- issue the 8 B gloads for k-window offset KO into LDS
#define B_STAGE(KO)                                                            \
    {                                                                          \
        _Pragma("unroll")                                                      \
        for (int q = 0; q < 4; ++q) {                                          \
            const int so = (tid + 256 * q) * 8;   /* elem offset (16 B) */     \
            const int go = (KO) + 16 * q;         /* kc=(tid>>7)+2q -> +16q */ \
            gload_lds16(WB0 + go, &Bs[0][0][0][0] + so);                       \
            gload_lds16(WB1 + go, &Bs[1][0][0][0] + so);                       \
        }                                                                      \
    }

    // ---- split2 the 32 X floats (x0..x7) and write the A tile
#define A_STAGE()                                                              \
    {                                                                          \
        float xv[32] = {x0.x, x0.y, x0.z, x0.w, x1.x, x1.y, x1.z, x1.w,        \
                        x2.x, x2.y, x2.z, x2.w, x3.x, x3.y, x3.z, x3.w,        \
                        x4.x, x4.y, x4.z, x4.w, x5.x, x5.y, x5.z, x5.w,        \
                        x6.x, x6.y, x6.z, x6.w, x7.x, x7.y, x7.z, x7.w};       \
        _Pragma("unroll")                                                      \
        for (int c = 0; c < 4; ++c) {                                          \
            u16x8 vh, vm;                                                      \
            _Pragma("unroll")                                                  \
            for (int t = 0; t < 8; ++t) {                                      \
                unsigned short h, m;                                           \
                split2(xv[c * 8 + t] * 64.f, h, m);                            \
                vh[t] = h; vm[t] = m;                                          \
            }                                                                  \
            *(u16x8*)&As[0][kc0 + c][srow][0] = vh;                            \
            *(u16x8*)&As[1][kc0 + c][srow][0] = vm;                            \
        }                                                                      \
    }

#define X_LOAD(KO)                                                             \
    {                                                                          \
        const float* xn = Xp + (KO);                                           \
        x0 = *(const float4*)(xn + 0);   x1 = *(const float4*)(xn + 4);        \
        x2 = *(const float4*)(xn + 8);   x3 = *(const float4*)(xn + 12);       \
        x4 = *(const float4*)(xn + 16);  x5 = *(const float4*)(xn + 20);       \
        x6 = *(const float4*)(xn + 24);  x7 = *(const float4*)(xn + 28);       \
    }

    // ---- prologue: B(0), X(0), A_STAGE(0), X(1), drain-B barrier
    float4 x0, x1, x2, x3, x4, x5, x6, x7;
    B_STAGE(0);
    X_LOAD(0);
    A_STAGE();
    if (NK > 1) X_LOAD(64);
    asm volatile("s_waitcnt vmcnt(8) lgkmcnt(0)" ::: "memory");
    __builtin_amdgcn_s_barrier();

    for (int kt = 0; kt < NK; ++kt) {
        // ---- MFMA on tile kt: two 32-k halves, 3 passes each
#pragma unroll
        for (int s = 0; s < 2; ++s) {
            const int s4 = s * 4 + fkc;
            f16x8 afh[4], afm[4], bfh[4], bfm[4];
#pragma unroll
            for (int i = 0; i < 4; ++i) {
                afh[i] = *(const f16x8*)&As[0][s4][wm * 64 + i * 16 + frow][0];
                bfh[i] = *(const f16x8*)&Bs[0][s4][wn * 64 + i * 16 + frow][0];
                afm[i] = *(const f16x8*)&As[1][s4][wm * 64 + i * 16 + frow][0];
                bfm[i] = *(const f16x8*)&Bs[1][s4][wn * 64 + i * 16 + frow][0];
            }
            __builtin_amdgcn_s_setprio(1);
#pragma unroll
            for (int i = 0; i < 4; ++i)
#pragma unroll
                for (int j = 0; j < 4; ++j)
                    acc[i][j] = __builtin_amdgcn_mfma_f32_16x16x32_f16(
                        afh[i], bfh[j], acc[i][j], 0, 0, 0);      // hh
#pragma unroll
            for (int i = 0; i < 4; ++i)
#pragma unroll
                for (int j = 0; j < 4; ++j)
                    acc[i][j] = __builtin_amdgcn_mfma_f32_16x16x32_f16(
                        afh[i], bfm[j], acc[i][j], 0, 0, 0);      // hm
#pragma unroll
            for (int i = 0; i < 4; ++i)
#pragma unroll
                for (int j = 0; j < 4; ++j)
                    acc[i][j] = __builtin_amdgcn_mfma_f32_16x16x32_f16(
                        afm[i], bfh[j], acc[i][j], 0, 0, 0);      // mh
            __builtin_amdgcn_s_setprio(0);
        }

        // ---- stage tile kt+1
        if (kt + 1 < NK) {
            __builtin_amdgcn_s_barrier();          // all waves done reading kt
            B_STAGE((kt + 1) * 64);
            A_STAGE();                             // consumes X(kt+1) regs
            if (kt + 2 < NK) {
                X_LOAD((kt + 2) * 64);             // into freed regs
                asm volatile("s_waitcnt vmcnt(8) lgkmcnt(0)" ::: "memory");
            } else {
                asm volatile("s_waitcnt vmcnt(0) lgkmcnt(0)" ::: "memory");
            }
            __builtin_amdgcn_s_barrier();
        }
    }
#undef B_STAGE
#undef A_STAGE
#undef X_LOAD

    // ---- epilogue: D layout col=lane&15, row=(lane>>4)*4+r
    float* Cz = Cp + (size_t)kz * T_TOK * E;
    const int rbase = (lane >> 4) * 4;
#pragma unroll
    for (int i = 0; i < 4; ++i)
#pragma unroll
        for (int j = 0; j < 4; ++j) {
            const int ecol = eb + wn * 64 + j * 16 + frow;
#pragma unroll
            for (int r = 0; r < 4; ++r) {
                const int tok = TB + wm * 64 + i * 16 + rbase + r;
                Cz[(size_t)tok * E + ecol] = acc[i][j][r];
            }
        }
}

// ---------------------------------------------------------------------------
// Kernel 2: fused split-K reduce + routing (proven). 16 lanes/token, 16
// experts/lane, all in registers; exact lax.top_k tie-breaks. Logits are
// scaled by 2^14 (X*64, W*256) -> multiply by 2^-14 (exact) before sigmoid.
// ---------------------------------------------------------------------------
__global__ __launch_bounds__(256) void route_kernel(const float* __restrict__ P,
                                                    const float* __restrict__ bias,
                                                    float* __restrict__ out,
                                                    int nsplit) {
    const int sub = threadIdx.x & 15;
    const int tok = blockIdx.x * 16 + (threadIdx.x >> 4);
    const int ebase = sub * 16;

    double accd[16];
#pragma unroll
    for (int i = 0; i < 16; ++i) accd[i] = 0.0;
    for (int s = 0; s < nsplit; ++s) {
        const float* base = P + (size_t)s * T_TOK * E + (size_t)tok * E + ebase;
#pragma unroll
        for (int v = 0; v < 4; ++v) {
            float4 f = *(const float4*)(base + v * 4);
            accd[v * 4 + 0] += (double)f.x; accd[v * 4 + 1] += (double)f.y;
            accd[v * 4 + 2] += (double)f.z; accd[v * 4 + 3] += (double)f.w;
        }
    }

    float us[16], sc[16];
#pragma unroll
    for (int i = 0; i < 16; ++i) {
        float lg = (float)accd[i] * (1.f / 16384.f);   // exact pow2 unscale
        double s = 1.0 / (1.0 + exp(-(double)lg));
        us[i] = (float)s;
        sc[i] = us[i] + bias[ebase + i];
    }

    float m1 = -1e30f, m2 = -1e30f;
#pragma unroll
    for (int i = 0; i < 16; ++i) {
        float s = sc[i];
        if (s > m1)      { m2 = m1; m1 = s; }
        else if (s > m2) { m2 = s; }
    }
    float pm1 = __shfl_xor(m1, 1, 16);
    float pm2 = __shfl_xor(m2, 1, 16);
    float gsum = (m1 >= pm1) ? (m1 + fmaxf(m2, pm1)) : (pm1 + fmaxf(pm2, m1));

    const int g = sub >> 1;
    int rank = 0;
#pragma unroll
    for (int h = 0; h < 8; ++h) {
        float gh = __shfl(gsum, h * 2, 16);
        if (h != g && (gh > gsum || (gh == gsum && h < g))) ++rank;
    }
    const bool sel = (rank < 4);

    unsigned used = 0;
    float myoi = 0.f, myow = 0.f;
    float wsum = 0.f;
#pragma unroll
    for (int p = 0; p < 8; ++p) {
        float bv = -1e30f; int bi = 0x7fff; float bu = 0.f;
#pragma unroll
        for (int i = 0; i < 16; ++i) {
            float v = ((used >> i) & 1u) ? -1e30f : (sel ? sc[i] : 0.0f);
            if (v > bv || (v == bv && (ebase + i) < bi)) {
                bv = v; bi = ebase + i; bu = us[i];
            }
        }
#pragma unroll
        for (int d = 1; d < 16; d <<= 1) {
            float ov = __shfl_xor(bv, d, 16);
            int   oi = __shfl_xor(bi, d, 16);
            float ou = __shfl_xor(bu, d, 16);
            if (ov > bv || (ov == bv && oi < bi)) { bv = ov; bi = oi; bu = ou; }
        }
        if ((bi >> 4) == sub) used |= 1u << (bi & 15);
        if (sub == p) { myoi = (float)bi; myow = bu; }
        wsum += bu;
    }

    const float scale = 2.5f / (wsum + 1e-20f);
    if (sub < 8) {
        out[(size_t)tok * 8 + sub] = myoi;
        out[(size_t)T_TOK * 8 + (size_t)tok * 8 + sub] = myow * scale;
    }
}

// ---------------------------------------------------------------------------
extern "C" void kernel_launch(void* const* d_in, const int* in_sizes, int n_in,
                              void* d_out, int out_size, void* d_ws, size_t ws_size,
                              hipStream_t stream) {
    const float* X = (const float*)d_in[0];   // [4,4096,2048] fp32
    const float* W = (const float*)d_in[1];   // [256,2048]   fp32
    const float* B = (const float*)d_in[2];   // [256]        fp32
    float* out     = (float*)d_out;

    const size_t WE     = (size_t)E * H;                       // 524288
    const size_t planeB = WE * sizeof(unsigned short);         // 1 MB
    const size_t chunkB = (size_t)T_TOK * E * sizeof(float);   // 16 MB

    unsigned short* Wh = (unsigned short*)d_ws;
    unsigned short* Wm = Wh + WE;
    float* part = (float*)((char*)d_ws + 2 * planeB);

    int nsplit = 1;
    if (ws_size >= 2 * planeB + 4 * chunkB)      nsplit = 4;
    else if (ws_size >= 2 * planeB + 2 * chunkB) nsplit = 2;
    const int klen = H / nsplit;

    prep_w<<<WE / (256 * 4), 256, 0, stream>>>(W, Wh, Wm);

    dim3 gg(E / 128, T_TOK / 128, nsplit);    // (2, 128, 4) = 1024 blocks
    gemm_logits<<<gg, 256, 0, stream>>>(X, Wh, Wm, part, klen);

    route_kernel<<<T_TOK / 16, 256, 0, stream>>>(part, B, out, nsplit);
}

// Round 14
// 114.921 us; speedup vs baseline: 1.1913x; 1.1913x over previous
//
#include <hip/hip_runtime.h>
#include <hip/hip_bf16.h>
#include <math.h>

static constexpr int T_TOK = 16384;   // 4*4096 tokens
static constexpr int E     = 256;     // experts
static constexpr int H     = 2048;    // hidden dim

typedef __attribute__((ext_vector_type(8))) _Float16       f16x8;
typedef __attribute__((ext_vector_type(8))) unsigned short u16x8;
typedef __attribute__((ext_vector_type(4))) float          f32x4;

// 2-way f16 split of a PRE-SCALED value: xs == h + m + eps, |eps| <~ 2^-22|xs|.
__device__ __forceinline__ void split2(float xs, unsigned short& h,
                                       unsigned short& m) {
    _Float16 hh = (_Float16)xs;        // RN f32->f16
    float fh = (float)hh;
    float r  = xs - fh;                // exact in f32
    _Float16 mm = (_Float16)r;         // RN
    h = *(unsigned short*)&hh; m = *(unsigned short*)&mm;
}

// async 16B global -> LDS (dest = wave-uniform base + lane*16)
__device__ __forceinline__ void gload_lds16(const unsigned short* g,
                                            unsigned short* l) {
    __builtin_amdgcn_global_load_lds(
        (const __attribute__((address_space(1))) unsigned int*)g,
        (__attribute__((address_space(3))) unsigned int*)l, 16, 0, 0);
}

// ---------------------------------------------------------------------------
// Kernel 0: split W*256 [256][2048] fp32 into two f16 planes (same layout).
// ---------------------------------------------------------------------------
__global__ __launch_bounds__(256) void prep_w(const float* __restrict__ W,
                                              unsigned short* __restrict__ Wh,
                                              unsigned short* __restrict__ Wm) {
    const int i = (blockIdx.x * 256 + threadIdx.x) * 4;
    float4 x = *(const float4*)(W + i);
    unsigned short h[4], m[4];
    split2(x.x * 256.f, h[0], m[0]);
    split2(x.y * 256.f, h[1], m[1]);
    split2(x.z * 256.f, h[2], m[2]);
    split2(x.w * 256.f, h[3], m[3]);
#pragma unroll
    for (int q = 0; q < 4; ++q) { Wh[i+q] = h[q]; Wm[i+q] = m[q]; }
}

// ---------------------------------------------------------------------------
// Kernel 1: partial logits via f16x2 MFMA, THREE passes (hh,hm,mh — mm term
// is ~6e-8 on unit logits, validated to pass in round 13).
// Block = 128 tokens x 128 experts, 256 threads (4 waves, 2Mx2N), wave tile
// 64x64 = 4x4 frags of mfma_f32_16x16x32_f16. BK=32. Split-K over z.
// R12 structure (best measured: ~110 us gemm, FETCH 135 MB) with ONE fix:
// X(kt+1) is issued AFTER sync2, so its ~900-cyc HBM latency hides under
// the whole MFMA phase instead of being force-drained by sync2 with only
// ~150 cyc of cover (the R12 drain bug). B gloads stay at the top of the
// step: L2-resident, covered by the 96-VALU A_STAGE before sync2.
// ---------------------------------------------------------------------------
__global__ __launch_bounds__(256) void gemm_logits(
        const float* __restrict__ X,
        const unsigned short* __restrict__ Wh,
        const unsigned short* __restrict__ Wm,
        float* __restrict__ Cp, int klen) {
    __shared__ __align__(16) unsigned short As[2][4][128][8];   // 16 KB
    __shared__ __align__(16) unsigned short Bs[2][4][128][8];   // 16 KB

    const int tid  = threadIdx.x;
    const int lane = tid & 63;
    const int wid  = tid >> 6;            // 0..3
    const int wm   = wid >> 1, wn = wid & 1;   // 2M x 2N
    const int kz   = blockIdx.z;
    const int kbase = kz * klen;
    const int TB   = blockIdx.y * 128;
    const int eb   = blockIdx.x * 128;

    // A staging: thread owns row=tid>>1 (0..127), k-half=(tid&1)*16
    const int srow = tid >> 1;
    const int kc0  = (tid & 1) * 2;
    const float* Xp = X + (size_t)(TB + srow) * H + kbase + (tid & 1) * 16;

    // B staging: 2 gloads per plane; LDS linear slot tid and tid+256
    const int brow = tid & 127;
    const int bkc  = tid >> 7;            // 0..1
    const unsigned short* WB0 = Wh + (size_t)(eb + brow) * H + kbase + bkc * 8;
    const unsigned short* WB1 = Wm + (size_t)(eb + brow) * H + kbase + bkc * 8;
    const int eOffB0 = tid * 8;           // elements (16 B)
    const int eOffB1 = (tid + 256) * 8;   // covers kc+2, same row

    const int frow = lane & 15;
    const int fkc  = lane >> 4;           // k-chunk 0..3

    f32x4 acc[4][4];
#pragma unroll
    for (int i = 0; i < 4; ++i)
#pragma unroll
        for (int j = 0; j < 4; ++j) acc[i][j] = (f32x4){0.f, 0.f, 0.f, 0.f};

    const int NK = klen / 32;             // nsplit 4/2/1 -> 16/32/64, even

    // ---- scale by 64, split2, write the A tile (2 planes x 2 chunks)
#define A_STAGE(q0, q1, q2, q3)                                                \
    {                                                                          \
        float xv[16] = {q0.x, q0.y, q0.z, q0.w, q1.x, q1.y, q1.z, q1.w,        \
                        q2.x, q2.y, q2.z, q2.w, q3.x, q3.y, q3.z, q3.w};       \
        u16x8 vh0, vh1, vm0, vm1;                                              \
        _Pragma("unroll")                                                      \
        for (int t = 0; t < 8; ++t) {                                          \
            unsigned short h, m;                                               \
            split2(xv[t] * 64.f, h, m);                                        \
            vh0[t] = h; vm0[t] = m;                                            \
        }                                                                      \
        _Pragma("unroll")                                                      \
        for (int t = 0; t < 8; ++t) {                                          \
            unsigned short h, m;                                               \
            split2(xv[8 + t] * 64.f, h, m);                                    \
            vh1[t] = h; vm1[t] = m;                                            \
        }                                                                      \
        *(u16x8*)&As[0][kc0    ][srow][0] = vh0;                               \
        *(u16x8*)&As[0][kc0 + 1][srow][0] = vh1;                               \
        *(u16x8*)&As[1][kc0    ][srow][0] = vm0;                               \
        *(u16x8*)&As[1][kc0 + 1][srow][0] = vm1;                               \
    }

    // ---- one K-step (single-buffered; C* = X regs for THIS step, N* = next)
#define KSTEP(KT, C0, C1, C2, C3, N0, N1, N2, N3)                              \
    {                                                                          \
        __syncthreads();   /* prior frag reads done; X(KT) landed long ago */  \
        {                                                                      \
            const int ko = (KT) * 32;                                          \
            gload_lds16(WB0 + ko,      &Bs[0][0][0][0] + eOffB0);              \
            gload_lds16(WB0 + ko + 16, &Bs[0][0][0][0] + eOffB1);              \
            gload_lds16(WB1 + ko,      &Bs[1][0][0][0] + eOffB0);              \
            gload_lds16(WB1 + ko + 16, &Bs[1][0][0][0] + eOffB1);              \
        }                                                                      \
        A_STAGE(C0, C1, C2, C3);   /* ~200+ cyc of cover for the B gloads */   \
        __syncthreads();   /* B gloads + A writes visible */                   \
        if ((KT) + 1 < NK) {       /* issue X(KT+1) NOW: flies under MFMAs */  \
            const float* xn = Xp + ((KT) + 1) * 32;                            \
            N0 = *(const float4*)(xn + 0);  N1 = *(const float4*)(xn + 4);     \
            N2 = *(const float4*)(xn + 8);  N3 = *(const float4*)(xn + 12);    \
        }                                                                      \
        f16x8 afh[4], afm[4], bfh[4], bfm[4];                                  \
        _Pragma("unroll")                                                      \
        for (int i = 0; i < 4; ++i) {                                          \
            afh[i] = *(const f16x8*)&As[0][fkc][wm * 64 + i * 16 + frow][0];   \
            bfh[i] = *(const f16x8*)&Bs[0][fkc][wn * 64 + i * 16 + frow][0];   \
            afm[i] = *(const f16x8*)&As[1][fkc][wm * 64 + i * 16 + frow][0];   \
            bfm[i] = *(const f16x8*)&Bs[1][fkc][wn * 64 + i * 16 + frow][0];   \
        }                                                                      \
        __builtin_amdgcn_s_setprio(1);                                         \
        _Pragma("unroll")                                                      \
        for (int i = 0; i < 4; ++i)                                            \
            _Pragma("unroll")                                                  \
            for (int j = 0; j < 4; ++j)                                        \
                acc[i][j] = __builtin_amdgcn_mfma_f32_16x16x32_f16(            \
                    afh[i], bfh[j], acc[i][j], 0, 0, 0);   /* hh */            \
        _Pragma("unroll")                                                      \
        for (int i = 0; i < 4; ++i)                                            \
            _Pragma("unroll")                                                  \
            for (int j = 0; j < 4; ++j)                                        \
                acc[i][j] = __builtin_amdgcn_mfma_f32_16x16x32_f16(            \
                    afh[i], bfm[j], acc[i][j], 0, 0, 0);   /* hm */            \
        _Pragma("unroll")                                                      \
        for (int i = 0; i < 4; ++i)                                            \
            _Pragma("unroll")                                                  \
            for (int j = 0; j < 4; ++j)                                        \
                acc[i][j] = __builtin_amdgcn_mfma_f32_16x16x32_f16(            \
                    afm[i], bfh[j], acc[i][j], 0, 0, 0);   /* mh */            \
        __builtin_amdgcn_s_setprio(0);                                         \
    }

    // ---- prologue: X(0) sync load into ping regs
    float4 pa0, pa1, pa2, pa3, pb0, pb1, pb2, pb3;
    pa0 = *(const float4*)(Xp + 0);  pa1 = *(const float4*)(Xp + 4);
    pa2 = *(const float4*)(Xp + 8);  pa3 = *(const float4*)(Xp + 12);

    for (int kt = 0; kt < NK; kt += 2) {
        KSTEP(kt,     pa0, pa1, pa2, pa3, pb0, pb1, pb2, pb3);
        KSTEP(kt + 1, pb0, pb1, pb2, pb3, pa0, pa1, pa2, pa3);
    }
#undef KSTEP
#undef A_STAGE

    // ---- epilogue: D layout col=lane&15, row=(lane>>4)*4+r
    float* Cz = Cp + (size_t)kz * T_TOK * E;
    const int rbase = (lane >> 4) * 4;
#pragma unroll
    for (int i = 0; i < 4; ++i)
#pragma unroll
        for (int j = 0; j < 4; ++j) {
            const int ecol = eb + wn * 64 + j * 16 + frow;
#pragma unroll
            for (int r = 0; r < 4; ++r) {
                const int tok = TB + wm * 64 + i * 16 + rbase + r;
                Cz[(size_t)tok * E + ecol] = acc[i][j][r];
            }
        }
}

// ---------------------------------------------------------------------------
// Kernel 2: fused split-K reduce + routing (proven). 16 lanes/token, 16
// experts/lane, all in registers; exact lax.top_k tie-breaks. Logits are
// scaled by 2^14 (X*64, W*256) -> multiply by 2^-14 (exact) before sigmoid.
// ---------------------------------------------------------------------------
__global__ __launch_bounds__(256) void route_kernel(const float* __restrict__ P,
                                                    const float* __restrict__ bias,
                                                    float* __restrict__ out,
                                                    int nsplit) {
    const int sub = threadIdx.x & 15;
    const int tok = blockIdx.x * 16 + (threadIdx.x >> 4);
    const int ebase = sub * 16;

    double accd[16];
#pragma unroll
    for (int i = 0; i < 16; ++i) accd[i] = 0.0;
    for (int s = 0; s < nsplit; ++s) {
        const float* base = P + (size_t)s * T_TOK * E + (size_t)tok * E + ebase;
#pragma unroll
        for (int v = 0; v < 4; ++v) {
            float4 f = *(const float4*)(base + v * 4);
            accd[v * 4 + 0] += (double)f.x; accd[v * 4 + 1] += (double)f.y;
            accd[v * 4 + 2] += (double)f.z; accd[v * 4 + 3] += (double)f.w;
        }
    }

    float us[16], sc[16];
#pragma unroll
    for (int i = 0; i < 16; ++i) {
        float lg = (float)accd[i] * (1.f / 16384.f);   // exact pow2 unscale
        double s = 1.0 / (1.0 + exp(-(double)lg));
        us[i] = (float)s;
        sc[i] = us[i] + bias[ebase + i];
    }

    float m1 = -1e30f, m2 = -1e30f;
#pragma unroll
    for (int i = 0; i < 16; ++i) {
        float s = sc[i];
        if (s > m1)      { m2 = m1; m1 = s; }
        else if (s > m2) { m2 = s; }
    }
    float pm1 = __shfl_xor(m1, 1, 16);
    float pm2 = __shfl_xor(m2, 1, 16);
    float gsum = (m1 >= pm1) ? (m1 + fmaxf(m2, pm1)) : (pm1 + fmaxf(pm2, m1));

    const int g = sub >> 1;
    int rank = 0;
#pragma unroll
    for (int h = 0; h < 8; ++h) {
        float gh = __shfl(gsum, h * 2, 16);
        if (h != g && (gh > gsum || (gh == gsum && h < g))) ++rank;
    }
    const bool sel = (rank < 4);

    unsigned used = 0;
    float myoi = 0.f, myow = 0.f;
    float wsum = 0.f;
#pragma unroll
    for (int p = 0; p < 8; ++p) {
        float bv = -1e30f; int bi = 0x7fff; float bu = 0.f;
#pragma unroll
        for (int i = 0; i < 16; ++i) {
            float v = ((used >> i) & 1u) ? -1e30f : (sel ? sc[i] : 0.0f);
            if (v > bv || (v == bv && (ebase + i) < bi)) {
                bv = v; bi = ebase + i; bu = us[i];
            }
        }
#pragma unroll
        for (int d = 1; d < 16; d <<= 1) {
            float ov = __shfl_xor(bv, d, 16);
            int   oi = __shfl_xor(bi, d, 16);
            float ou = __shfl_xor(bu, d, 16);
            if (ov > bv || (ov == bv && oi < bi)) { bv = ov; bi = oi; bu = ou; }
        }
        if ((bi >> 4) == sub) used |= 1u << (bi & 15);
        if (sub == p) { myoi = (float)bi; myow = bu; }
        wsum += bu;
    }

    const float scale = 2.5f / (wsum + 1e-20f);
    if (sub < 8) {
        out[(size_t)tok * 8 + sub] = myoi;
        out[(size_t)T_TOK * 8 + (size_t)tok * 8 + sub] = myow * scale;
    }
}

// ---------------------------------------------------------------------------
extern "C" void kernel_launch(void* const* d_in, const int* in_sizes, int n_in,
                              void* d_out, int out_size, void* d_ws, size_t ws_size,
                              hipStream_t stream) {
    const float* X = (const float*)d_in[0];   // [4,4096,2048] fp32
    const float* W = (const float*)d_in[1];   // [256,2048]   fp32
    const float* B = (const float*)d_in[2];   // [256]        fp32
    float* out     = (float*)d_out;

    const size_t WE     = (size_t)E * H;                       // 524288
    const size_t planeB = WE * sizeof(unsigned short);         // 1 MB
    const size_t chunkB = (size_t)T_TOK * E * sizeof(float);   // 16 MB

    unsigned short* Wh = (unsigned short*)d_ws;
    unsigned short* Wm = Wh + WE;
    float* part = (float*)((char*)d_ws + 2 * planeB);

    int nsplit = 1;
    if (ws_size >= 2 * planeB + 4 * chunkB)      nsplit = 4;
    else if (ws_size >= 2 * planeB + 2 * chunkB) nsplit = 2;
    const int klen = H / nsplit;

    prep_w<<<WE / (256 * 4), 256, 0, stream>>>(W, Wh, Wm);

    dim3 gg(E / 128, T_TOK / 128, nsplit);    // (2, 128, 4) = 1024 blocks
    gemm_logits<<<gg, 256, 0, stream>>>(X, Wh, Wm, part, klen);

    route_kernel<<<T_TOK / 16, 256, 0, stream>>>(part, B, out, nsplit);
}

// Round 15
// 108.369 us; speedup vs baseline: 1.2634x; 1.0605x over previous
//
#include <hip/hip_runtime.h>
#include <hip/hip_bf16.h>
#include <math.h>

static constexpr int T_TOK = 16384;   // 4*4096 tokens
static constexpr int E     = 256;     // experts
static constexpr int H     = 2048;    // hidden dim

typedef __attribute__((ext_vector_type(8))) _Float16       f16x8;
typedef __attribute__((ext_vector_type(8))) unsigned short u16x8;
typedef __attribute__((ext_vector_type(4))) float          f32x4;

// 2-way f16 split of a PRE-SCALED value: xs == h + m + eps, |eps| <~ 2^-22|xs|.
__device__ __forceinline__ void split2(float xs, unsigned short& h,
                                       unsigned short& m) {
    _Float16 hh = (_Float16)xs;        // RN f32->f16
    float fh = (float)hh;
    float r  = xs - fh;                // exact in f32
    _Float16 mm = (_Float16)r;         // RN
    h = *(unsigned short*)&hh; m = *(unsigned short*)&mm;
}

// async 16B global -> LDS (dest = wave-uniform base + lane*16)
__device__ __forceinline__ void gload_lds16(const unsigned short* g,
                                            unsigned short* l) {
    __builtin_amdgcn_global_load_lds(
        (const __attribute__((address_space(1))) unsigned int*)g,
        (__attribute__((address_space(3))) unsigned int*)l, 16, 0, 0);
}

// ---------------------------------------------------------------------------
// Kernel 0: split W*256 [256][2048] fp32 into two f16 planes (same layout).
// ---------------------------------------------------------------------------
__global__ __launch_bounds__(256) void prep_w(const float* __restrict__ W,
                                              unsigned short* __restrict__ Wh,
                                              unsigned short* __restrict__ Wm) {
    const int i = (blockIdx.x * 256 + threadIdx.x) * 4;
    float4 x = *(const float4*)(W + i);
    unsigned short h[4], m[4];
    split2(x.x * 256.f, h[0], m[0]);
    split2(x.y * 256.f, h[1], m[1]);
    split2(x.z * 256.f, h[2], m[2]);
    split2(x.w * 256.f, h[3], m[3]);
#pragma unroll
    for (int q = 0; q < 4; ++q) { Wh[i+q] = h[q]; Wm[i+q] = m[q]; }
}

// ---------------------------------------------------------------------------
// Kernel 1: partial logits via f16x2 MFMA, THREE passes (hh,hm,mh).
// OCCUPANCY RE-TILE (round-15): 512 threads = 8 waves (2M x 4N), wave tile
// 64x32 -> acc[4][2] = 32 AGPR (was 64). Per-thread staging halves (8 X
// floats). Target total regs <= 128 -> 4 waves/SIMD (was 1.6), enforced by
// __launch_bounds__(512, 4). Same 128x128 block tile, BK=32, 32 KB LDS,
// proven R12/R14 schedule: sync1 -> B gloads -> A_STAGE -> sync2 ->
// X(kt+1) issue (flies under MFMA phase) -> frag reads -> 24 MFMA/wave.
// ---------------------------------------------------------------------------
__global__ __launch_bounds__(512, 4) void gemm_logits(
        const float* __restrict__ X,
        const unsigned short* __restrict__ Wh,
        const unsigned short* __restrict__ Wm,
        float* __restrict__ Cp, int klen) {
    __shared__ __align__(16) unsigned short As[2][4][128][8];   // 16 KB
    __shared__ __align__(16) unsigned short Bs[2][4][128][8];   // 16 KB

    const int tid  = threadIdx.x;
    const int lane = tid & 63;
    const int wid  = tid >> 6;            // 0..7
    const int wm   = wid >> 2, wn = wid & 3;   // 2M x 4N; wave = 64 x 32
    const int kz   = blockIdx.z;
    const int kbase = kz * klen;
    const int TB   = blockIdx.y * 128;
    const int eb   = blockIdx.x * 128;

    // A staging: thread owns row=tid>>2 (0..127), k-chunk c=tid&3 (8 floats)
    const int srow = tid >> 2;
    const int sc   = tid & 3;
    const float* Xp = X + (size_t)(TB + srow) * H + kbase + sc * 8;

    // B staging: ONE 16B gload per plane; linear slot tid -> (kc=tid>>7,
    // row=tid&127); global source per-lane mapped to match.
    const int brow = tid & 127;
    const int bkc  = tid >> 7;            // 0..3
    const unsigned short* WB0 = Wh + (size_t)(eb + brow) * H + kbase + bkc * 8;
    const unsigned short* WB1 = Wm + (size_t)(eb + brow) * H + kbase + bkc * 8;
    const int eOffB = tid * 8;            // elements (16 B)

    const int frow = lane & 15;
    const int fkc  = lane >> 4;           // k-chunk 0..3

    f32x4 acc[4][2];
#pragma unroll
    for (int i = 0; i < 4; ++i)
#pragma unroll
        for (int j = 0; j < 2; ++j) acc[i][j] = (f32x4){0.f, 0.f, 0.f, 0.f};

    const int NK = klen / 32;             // nsplit 4/2/1 -> 16/32/64, even

    // ---- scale by 64, split2 the thread's 8 floats, write one A chunk
#define A_STAGE(q0, q1)                                                        \
    {                                                                          \
        float xv[8] = {q0.x, q0.y, q0.z, q0.w, q1.x, q1.y, q1.z, q1.w};        \
        u16x8 vh, vm;                                                          \
        _Pragma("unroll")                                                      \
        for (int t = 0; t < 8; ++t) {                                          \
            unsigned short h, m;                                               \
            split2(xv[t] * 64.f, h, m);                                        \
            vh[t] = h; vm[t] = m;                                              \
        }                                                                      \
        *(u16x8*)&As[0][sc][srow][0] = vh;                                     \
        *(u16x8*)&As[1][sc][srow][0] = vm;                                     \
    }

    // ---- one K-step (single-buffered; C* = X regs for THIS step, N* = next)
#define KSTEP(KT, C0, C1, N0, N1)                                              \
    {                                                                          \
        __syncthreads();   /* prior frag reads done; X(KT) landed long ago */  \
        {                                                                      \
            const int ko = (KT) * 32;                                          \
            gload_lds16(WB0 + ko, &Bs[0][0][0][0] + eOffB);                    \
            gload_lds16(WB1 + ko, &Bs[1][0][0][0] + eOffB);                    \
        }                                                                      \
        A_STAGE(C0, C1);                                                       \
        __syncthreads();   /* B gloads + A writes visible */                   \
        if ((KT) + 1 < NK) {       /* issue X(KT+1): flies under MFMAs */      \
            const float* xn = Xp + ((KT) + 1) * 32;                            \
            N0 = *(const float4*)(xn + 0);  N1 = *(const float4*)(xn + 4);     \
        }                                                                      \
        f16x8 afh[4], afm[4], bfh[2], bfm[2];                                  \
        _Pragma("unroll")                                                      \
        for (int i = 0; i < 4; ++i) {                                          \
            afh[i] = *(const f16x8*)&As[0][fkc][wm * 64 + i * 16 + frow][0];   \
            afm[i] = *(const f16x8*)&As[1][fkc][wm * 64 + i * 16 + frow][0];   \
        }                                                                      \
        _Pragma("unroll")                                                      \
        for (int j = 0; j < 2; ++j) {                                          \
            bfh[j] = *(const f16x8*)&Bs[0][fkc][wn * 32 + j * 16 + frow][0];   \
            bfm[j] = *(const f16x8*)&Bs[1][fkc][wn * 32 + j * 16 + frow][0];   \
        }                                                                      \
        __builtin_amdgcn_s_setprio(1);                                         \
        _Pragma("unroll")                                                      \
        for (int i = 0; i < 4; ++i)                                            \
            _Pragma("unroll")                                                  \
            for (int j = 0; j < 2; ++j)                                        \
                acc[i][j] = __builtin_amdgcn_mfma_f32_16x16x32_f16(            \
                    afh[i], bfh[j], acc[i][j], 0, 0, 0);   /* hh */            \
        _Pragma("unroll")                                                      \
        for (int i = 0; i < 4; ++i)                                            \
            _Pragma("unroll")                                                  \
            for (int j = 0; j < 2; ++j)                                        \
                acc[i][j] = __builtin_amdgcn_mfma_f32_16x16x32_f16(            \
                    afh[i], bfm[j], acc[i][j], 0, 0, 0);   /* hm */            \
        _Pragma("unroll")                                                      \
        for (int i = 0; i < 4; ++i)                                            \
            _Pragma("unroll")                                                  \
            for (int j = 0; j < 2; ++j)                                        \
                acc[i][j] = __builtin_amdgcn_mfma_f32_16x16x32_f16(            \
                    afm[i], bfh[j], acc[i][j], 0, 0, 0);   /* mh */            \
        __builtin_amdgcn_s_setprio(0);                                         \
    }

    // ---- prologue: X(0) sync load into ping regs
    float4 pa0, pa1, pb0, pb1;
    pa0 = *(const float4*)(Xp + 0);  pa1 = *(const float4*)(Xp + 4);

    for (int kt = 0; kt < NK; kt += 2) {
        KSTEP(kt,     pa0, pa1, pb0, pb1);
        KSTEP(kt + 1, pb0, pb1, pa0, pa1);
    }
#undef KSTEP
#undef A_STAGE

    // ---- epilogue: D layout col=lane&15, row=(lane>>4)*4+r
    float* Cz = Cp + (size_t)kz * T_TOK * E;
    const int rbase = (lane >> 4) * 4;
#pragma unroll
    for (int i = 0; i < 4; ++i)
#pragma unroll
        for (int j = 0; j < 2; ++j) {
            const int ecol = eb + wn * 32 + j * 16 + frow;
#pragma unroll
            for (int r = 0; r < 4; ++r) {
                const int tok = TB + wm * 64 + i * 16 + rbase + r;
                Cz[(size_t)tok * E + ecol] = acc[i][j][r];
            }
        }
}

// ---------------------------------------------------------------------------
// Kernel 2: fused split-K reduce + routing (proven). 16 lanes/token, 16
// experts/lane, all in registers; exact lax.top_k tie-breaks. Logits are
// scaled by 2^14 (X*64, W*256) -> multiply by 2^-14 (exact) before sigmoid.
// ---------------------------------------------------------------------------
__global__ __launch_bounds__(256) void route_kernel(const float* __restrict__ P,
                                                    const float* __restrict__ bias,
                                                    float* __restrict__ out,
                                                    int nsplit) {
    const int sub = threadIdx.x & 15;
    const int tok = blockIdx.x * 16 + (threadIdx.x >> 4);
    const int ebase = sub * 16;

    double accd[16];
#pragma unroll
    for (int i = 0; i < 16; ++i) accd[i] = 0.0;
    for (int s = 0; s < nsplit; ++s) {
        const float* base = P + (size_t)s * T_TOK * E + (size_t)tok * E + ebase;
#pragma unroll
        for (int v = 0; v < 4; ++v) {
            float4 f = *(const float4*)(base + v * 4);
            accd[v * 4 + 0] += (double)f.x; accd[v * 4 + 1] += (double)f.y;
            accd[v * 4 + 2] += (double)f.z; accd[v * 4 + 3] += (double)f.w;
        }
    }

    float us[16], sc[16];
#pragma unroll
    for (int i = 0; i < 16; ++i) {
        float lg = (float)accd[i] * (1.f / 16384.f);   // exact pow2 unscale
        double s = 1.0 / (1.0 + exp(-(double)lg));
        us[i] = (float)s;
        sc[i] = us[i] + bias[ebase + i];
    }

    float m1 = -1e30f, m2 = -1e30f;
#pragma unroll
    for (int i = 0; i < 16; ++i) {
        float s = sc[i];
        if (s > m1)      { m2 = m1; m1 = s; }
        else if (s > m2) { m2 = s; }
    }
    float pm1 = __shfl_xor(m1, 1, 16);
    float pm2 = __shfl_xor(m2, 1, 16);
    float gsum = (m1 >= pm1) ? (m1 + fmaxf(m2, pm1)) : (pm1 + fmaxf(pm2, m1));

    const int g = sub >> 1;
    int rank = 0;
#pragma unroll
    for (int h = 0; h < 8; ++h) {
        float gh = __shfl(gsum, h * 2, 16);
        if (h != g && (gh > gsum || (gh == gsum && h < g))) ++rank;
    }
    const bool sel = (rank < 4);

    unsigned used = 0;
    float myoi = 0.f, myow = 0.f;
    float wsum = 0.f;
#pragma unroll
    for (int p = 0; p < 8; ++p) {
        float bv = -1e30f; int bi = 0x7fff; float bu = 0.f;
#pragma unroll
        for (int i = 0; i < 16; ++i) {
            float v = ((used >> i) & 1u) ? -1e30f : (sel ? sc[i] : 0.0f);
            if (v > bv || (v == bv && (ebase + i) < bi)) {
                bv = v; bi = ebase + i; bu = us[i];
            }
        }
#pragma unroll
        for (int d = 1; d < 16; d <<= 1) {
            float ov = __shfl_xor(bv, d, 16);
            int   oi = __shfl_xor(bi, d, 16);
            float ou = __shfl_xor(bu, d, 16);
            if (ov > bv || (ov == bv && oi < bi)) { bv = ov; bi = oi; bu = ou; }
        }
        if ((bi >> 4) == sub) used |= 1u << (bi & 15);
        if (sub == p) { myoi = (float)bi; myow = bu; }
        wsum += bu;
    }

    const float scale = 2.5f / (wsum + 1e-20f);
    if (sub < 8) {
        out[(size_t)tok * 8 + sub] = myoi;
        out[(size_t)T_TOK * 8 + (size_t)tok * 8 + sub] = myow * scale;
    }
}

// ---------------------------------------------------------------------------
extern "C" void kernel_launch(void* const* d_in, const int* in_sizes, int n_in,
                              void* d_out, int out_size, void* d_ws, size_t ws_size,
                              hipStream_t stream) {
    const float* X = (const float*)d_in[0];   // [4,4096,2048] fp32
    const float* W = (const float*)d_in[1];   // [256,2048]   fp32
    const float* B = (const float*)d_in[2];   // [256]        fp32
    float* out     = (float*)d_out;

    const size_t WE     = (size_t)E * H;                       // 524288
    const size_t planeB = WE * sizeof(unsigned short);         // 1 MB
    const size_t chunkB = (size_t)T_TOK * E * sizeof(float);   // 16 MB

    unsigned short* Wh = (unsigned short*)d_ws;
    unsigned short* Wm = Wh + WE;
    float* part = (float*)((char*)d_ws + 2 * planeB);

    int nsplit = 1;
    if (ws_size >= 2 * planeB + 4 * chunkB)      nsplit = 4;
    else if (ws_size >= 2 * planeB + 2 * chunkB) nsplit = 2;
    const int klen = H / nsplit;

    prep_w<<<WE / (256 * 4), 256, 0, stream>>>(W, Wh, Wm);

    dim3 gg(E / 128, T_TOK / 128, nsplit);    // (2, 128, 4) = 1024 blocks
    gemm_logits<<<gg, 512, 0, stream>>>(X, Wh, Wm, part, klen);

    route_kernel<<<T_TOK / 16, 256, 0, stream>>>(part, B, out, nsplit);
}